// Round 1
// baseline (10203.809 us; speedup 1.0000x reference)
//
#include <hip/hip_runtime.h>
#include <math.h>

// Problem constants (fixed by the reference)
constexpr int BSZ = 2;
constexpr int SEQ = 2048;
constexpr int NE  = 2048;   // n_embd
constexpr int NH  = 16;
constexpr int HD  = 128;    // head_dim
constexpr int MROWS = BSZ * SEQ;  // 4096

// ---------------------------------------------------------------------------
// GEMM: C[M,N] = A[M,K] * B[K,N], row-major, fp32.
// 64x64 tile, BK=16, 256 threads (16x16), 4x4 micro-tile per thread.
// M%64==0, N%64==0, K%16==0 (all true here).
// ---------------------------------------------------------------------------
__global__ __launch_bounds__(256) void gemm_f32(const float* __restrict__ A,
                                                const float* __restrict__ B,
                                                float* __restrict__ C,
                                                int M, int N, int K)
{
    __shared__ float As[16][64];   // [k][m]
    __shared__ float Bs[16][64];   // [k][n]

    const int tx = threadIdx.x;            // 0..15 -> n
    const int ty = threadIdx.y;            // 0..15 -> m
    const int tid = ty * 16 + tx;          // 0..255
    const int m0 = blockIdx.y * 64;
    const int n0 = blockIdx.x * 64;

    // A staging: float4 from A[(m0 + tid/4)*K + k0 + (tid%4)*4]
    const int am = tid >> 2;               // 0..63
    const int ak = (tid & 3) * 4;          // 0,4,8,12
    // B staging: float4 from B[(k0 + tid/16)*N + n0 + (tid%16)*4]  (coalesced)
    const int bk = tid >> 4;               // 0..15
    const int bn = (tid & 15) * 4;

    float acc[4][4] = {};

    for (int k0 = 0; k0 < K; k0 += 16) {
        float4 av = *(const float4*)(A + (size_t)(m0 + am) * K + k0 + ak);
        float4 bv = *(const float4*)(B + (size_t)(k0 + bk) * N + n0 + bn);
        As[ak + 0][am] = av.x;
        As[ak + 1][am] = av.y;
        As[ak + 2][am] = av.z;
        As[ak + 3][am] = av.w;
        *(float4*)(&Bs[bk][bn]) = bv;
        __syncthreads();
#pragma unroll
        for (int k = 0; k < 16; ++k) {
            float4 a = *(const float4*)(&As[k][ty * 4]);
            float4 b = *(const float4*)(&Bs[k][tx * 4]);
            float ar[4] = {a.x, a.y, a.z, a.w};
            float br[4] = {b.x, b.y, b.z, b.w};
#pragma unroll
            for (int i = 0; i < 4; ++i)
#pragma unroll
                for (int j = 0; j < 4; ++j)
                    acc[i][j] += ar[i] * br[j];
        }
        __syncthreads();
    }

#pragma unroll
    for (int i = 0; i < 4; ++i) {
        float4 o = make_float4(acc[i][0], acc[i][1], acc[i][2], acc[i][3]);
        *(float4*)(C + (size_t)(m0 + ty * 4 + i) * N + n0 + tx * 4) = o;
    }
}

// ---------------------------------------------------------------------------
// RoPE in-place on Q and K (blockIdx.y selects which).
// Interleaved-pair convention: even' = x1*cos - x2*sin ; odd' = x1*sin + x2*cos
// ---------------------------------------------------------------------------
__global__ __launch_bounds__(256) void rope_kernel(float* __restrict__ Q,
                                                   float* __restrict__ K)
{
    const size_t npairs = (size_t)MROWS * NE / 2;  // 4M pairs per matrix
    size_t idx = (size_t)blockIdx.x * blockDim.x + threadIdx.x;
    if (idx >= npairs) return;
    float* P = blockIdx.y ? K : Q;

    const int r = (int)(idx / (NE / 2));     // row = b*SEQ + s
    const int c = (int)(idx % (NE / 2));     // pair index within row
    const int s = r % SEQ;                   // position
    const int n = 2 * c;                     // even element index in row
    const int i = (n % HD) / 2;              // freq index 0..63 within head

    const float expo = (2.0f * (float)i) / (float)HD;
    const float inv_freq = powf(10000.0f, -expo);
    const float f = (float)s * inv_freq;
    float sn, cs;
    sincosf(f, &sn, &cs);

    float* p = P + (size_t)r * NE + n;
    const float x1 = p[0];
    const float x2 = p[1];
    p[0] = x1 * cs - x2 * sn;
    p[1] = x1 * sn + x2 * cs;
}

// ---------------------------------------------------------------------------
// Attention: one block (256 thr) per (b, h, q-row). Causal. Online two-pass
// softmax with the whole score row staged in LDS (<= 8 KB).
// Q/K/V layout: [b*SEQ + s][h*HD + d]   (straight out of the GEMMs)
// Writes Y at the same layout. Y may alias Q (block reads only its own slice
// of Q, strictly before writing it).
// ---------------------------------------------------------------------------
__global__ __launch_bounds__(256) void attn_kernel(const float* __restrict__ Q,
                                                   const float* __restrict__ K,
                                                   const float* __restrict__ V,
                                                   float* __restrict__ Y)
{
    const int q  = blockIdx.x;          // 0..SEQ-1
    const int bh = blockIdx.y;          // 0..BSZ*NH-1
    const int b = bh / NH;
    const int h = bh % NH;
    const int tid = threadIdx.x;

    __shared__ float qv[HD];
    __shared__ float sc[SEQ];
    __shared__ float red[256];

    const float* Qrow = Q + ((size_t)(b * SEQ + q)) * NE + h * HD;
    if (tid < HD) qv[tid] = Qrow[tid];
    __syncthreads();

    const float scale = 0.088388347648318447f;  // 1/sqrt(128)

    // Phase 1: scores + local max
    const float* Kbase = K + (size_t)b * SEQ * NE + h * HD;
    float lmax = -INFINITY;
    for (int j = tid; j <= q; j += 256) {
        const float* Krow = Kbase + (size_t)j * NE;
        float s = 0.f;
#pragma unroll
        for (int d = 0; d < HD; d += 4) {
            float4 kk = *(const float4*)(Krow + d);
            float4 qq = *(const float4*)(qv + d);
            s += qq.x * kk.x + qq.y * kk.y + qq.z * kk.z + qq.w * kk.w;
        }
        s *= scale;
        sc[j] = s;
        lmax = fmaxf(lmax, s);
    }
    red[tid] = lmax;
    __syncthreads();
    for (int w = 128; w > 0; w >>= 1) {
        if (tid < w) red[tid] = fmaxf(red[tid], red[tid + w]);
        __syncthreads();
    }
    const float m = red[0];
    __syncthreads();

    // Phase 2: exp + sum
    float lsum = 0.f;
    for (int j = tid; j <= q; j += 256) {
        float p = expf(sc[j] - m);
        sc[j] = p;
        lsum += p;
    }
    red[tid] = lsum;
    __syncthreads();
    for (int w = 128; w > 0; w >>= 1) {
        if (tid < w) red[tid] += red[tid + w];
        __syncthreads();
    }
    const float inv = 1.0f / red[0];
    __syncthreads();

    // Phase 3: O[d] = sum_j p_j * V[j][d]; 2 j-partitions x 128 d-lanes
    const int d = tid & 127;
    const int half = tid >> 7;
    const float* Vb = V + (size_t)b * SEQ * NE + h * HD + d;
    float acc = 0.f;
    for (int j = half; j <= q; j += 2) {
        acc += sc[j] * Vb[(size_t)j * NE];
    }
    red[tid] = acc;
    __syncthreads();
    if (tid < 128) {
        float o = (red[tid] + red[tid + 128]) * inv;
        Y[((size_t)(b * SEQ + q)) * NE + h * HD + d] = o;
    }
}

// ---------------------------------------------------------------------------
extern "C" void kernel_launch(void* const* d_in, const int* in_sizes, int n_in,
                              void* d_out, int out_size, void* d_ws, size_t ws_size,
                              hipStream_t stream)
{
    const float* x  = (const float*)d_in[0];
    const float* wq = (const float*)d_in[1];
    const float* wk = (const float*)d_in[2];
    const float* wv = (const float*)d_in[3];
    const float* wo = (const float*)d_in[4];
    float* out = (float*)d_out;

    // Workspace: Q | K | V  (32 MB each). Y aliases Q.
    const size_t mat_elems = (size_t)MROWS * NE;  // 8M floats = 32 MB
    float* Q = (float*)d_ws;
    float* K = Q + mat_elems;
    float* V = K + mat_elems;
    float* Y = Q;  // alias, safe (see attn_kernel)

    dim3 gblk(16, 16);
    dim3 ggrd(NE / 64, MROWS / 64);  // (32, 64)

    gemm_f32<<<ggrd, gblk, 0, stream>>>(x, wq, Q, MROWS, NE, NE);
    gemm_f32<<<ggrd, gblk, 0, stream>>>(x, wk, K, MROWS, NE, NE);
    gemm_f32<<<ggrd, gblk, 0, stream>>>(x, wv, V, MROWS, NE, NE);

    const size_t npairs = (size_t)MROWS * NE / 2;
    dim3 rgrd((unsigned)((npairs + 255) / 256), 2);
    rope_kernel<<<rgrd, 256, 0, stream>>>(Q, K);

    dim3 agrd(SEQ, BSZ * NH);  // (2048, 32)
    attn_kernel<<<agrd, 256, 0, stream>>>(Q, K, V, Y);

    gemm_f32<<<ggrd, gblk, 0, stream>>>(Y, wo, out, MROWS, NE, NE);
}

// Round 2
// 3150.575 us; speedup vs baseline: 3.2387x; 3.2387x over previous
//
#include <hip/hip_runtime.h>
#include <math.h>

// Problem constants (fixed by the reference)
constexpr int BSZ = 2;
constexpr int SEQ = 2048;
constexpr int NE  = 2048;   // n_embd
constexpr int NH  = 16;
constexpr int HD  = 128;    // head_dim
constexpr int MROWS = BSZ * SEQ;  // 4096

// ---------------------------------------------------------------------------
// bf16 helpers (manual, version-independent)
// ---------------------------------------------------------------------------
__device__ __forceinline__ unsigned short f2bf(float f) {
    union { float f; unsigned u; } v; v.f = f;
    unsigned r = v.u + 0x7fffu + ((v.u >> 16) & 1u);   // round-to-nearest-even
    return (unsigned short)(r >> 16);
}
__device__ __forceinline__ float bflo(unsigned u) {     // low bf16 of packed u32
    union { unsigned u; float f; } v; v.u = u << 16; return v.f;
}
__device__ __forceinline__ float bfhi(unsigned u) {     // high bf16 of packed u32
    union { unsigned u; float f; } v; v.u = u & 0xffff0000u; return v.f;
}

// ---------------------------------------------------------------------------
// GEMM: C[M,N] = A[M,K] * B[K,N], row-major, fp32. (unchanged from R1)
// ---------------------------------------------------------------------------
__global__ __launch_bounds__(256) void gemm_f32(const float* __restrict__ A,
                                                const float* __restrict__ B,
                                                float* __restrict__ C,
                                                int M, int N, int K)
{
    __shared__ float As[16][64];   // [k][m]
    __shared__ float Bs[16][64];   // [k][n]

    const int tx = threadIdx.x;
    const int ty = threadIdx.y;
    const int tid = ty * 16 + tx;
    const int m0 = blockIdx.y * 64;
    const int n0 = blockIdx.x * 64;

    const int am = tid >> 2;
    const int ak = (tid & 3) * 4;
    const int bk = tid >> 4;
    const int bn = (tid & 15) * 4;

    float acc[4][4] = {};

    for (int k0 = 0; k0 < K; k0 += 16) {
        float4 av = *(const float4*)(A + (size_t)(m0 + am) * K + k0 + ak);
        float4 bv = *(const float4*)(B + (size_t)(k0 + bk) * N + n0 + bn);
        As[ak + 0][am] = av.x;
        As[ak + 1][am] = av.y;
        As[ak + 2][am] = av.z;
        As[ak + 3][am] = av.w;
        *(float4*)(&Bs[bk][bn]) = bv;
        __syncthreads();
#pragma unroll
        for (int k = 0; k < 16; ++k) {
            float4 a = *(const float4*)(&As[k][ty * 4]);
            float4 b = *(const float4*)(&Bs[k][tx * 4]);
            float ar[4] = {a.x, a.y, a.z, a.w};
            float br[4] = {b.x, b.y, b.z, b.w};
#pragma unroll
            for (int i = 0; i < 4; ++i)
#pragma unroll
                for (int j = 0; j < 4; ++j)
                    acc[i][j] += ar[i] * br[j];
        }
        __syncthreads();
    }

#pragma unroll
    for (int i = 0; i < 4; ++i) {
        float4 o = make_float4(acc[i][0], acc[i][1], acc[i][2], acc[i][3]);
        *(float4*)(C + (size_t)(m0 + ty * 4 + i) * N + n0 + tx * 4) = o;
    }
}

// ---------------------------------------------------------------------------
// RoPE in-place on Q and K (unchanged from R1)
// ---------------------------------------------------------------------------
__global__ __launch_bounds__(256) void rope_kernel(float* __restrict__ Q,
                                                   float* __restrict__ K)
{
    const size_t npairs = (size_t)MROWS * NE / 2;
    size_t idx = (size_t)blockIdx.x * blockDim.x + threadIdx.x;
    if (idx >= npairs) return;
    float* P = blockIdx.y ? K : Q;

    const int r = (int)(idx / (NE / 2));
    const int c = (int)(idx % (NE / 2));
    const int s = r % SEQ;
    const int n = 2 * c;
    const int i = (n % HD) / 2;

    const float expo = (2.0f * (float)i) / (float)HD;
    const float inv_freq = powf(10000.0f, -expo);
    const float f = (float)s * inv_freq;
    float sn, cs;
    sincosf(f, &sn, &cs);

    float* p = P + (size_t)r * NE + n;
    const float x1 = p[0];
    const float x2 = p[1];
    p[0] = x1 * cs - x2 * sn;
    p[1] = x1 * sn + x2 * cs;
}

// ---------------------------------------------------------------------------
// Flash attention: one block = one (b,h) x 64-row Q-tile. Causal.
// 256 threads, tx = tid&15, ty = tid>>4.
//   S micro-tile: thread owns rows 4ty+i (i<4), cols 4tx+j (j<4) of 64x64 S.
//   PV micro-tile: thread owns rows 4ty+i, d-cols 8tx+jj (jj<8) of 64x128 O.
// LDS: Qs/Ks d-major bf16 (stride 68 for 8B alignment + bank spread),
//      Vs k-major bf16 (stride 136), Ps k-major bf16 (stride 68). 59.5 KB.
// Y may alias Q: each (row, h-slice) is read only by the block that writes it.
// ---------------------------------------------------------------------------
__global__ __launch_bounds__(256) void flash_attn(const float* __restrict__ Qg,
                                                  const float* __restrict__ Kg,
                                                  const float* __restrict__ Vg,
                                                  float* __restrict__ Yg)
{
    const int qt = blockIdx.x;         // q-tile index, 0..31
    const int bh = blockIdx.y;         // 0..31
    const int b  = bh >> 4;
    const int h  = bh & 15;
    const int tid = threadIdx.x;
    const int tx = tid & 15;
    const int ty = tid >> 4;

    __shared__ unsigned short Qs[128][68];   // [d][q]  17408 B
    __shared__ unsigned short Ks[128][68];   // [d][k]  17408 B
    __shared__ unsigned short Vs[64][136];   // [k][d]  17408 B
    __shared__ unsigned short Ps[64][68];    // [k][q]   8704 B

    const int q0 = qt * 64;
    const size_t base = (size_t)b * SEQ * NE + (size_t)h * HD;
    const float scale = 0.088388347648318447f;  // 1/sqrt(128)

    // ---- Load Q tile (scale folded in), transpose to Qs[d][q] ----
    {
        const int kk = tid >> 2;          // 0..63 (row within tile)
        const int dg = (tid & 3) * 4;     // 0,4,8,12
        const float* src = Qg + base + (size_t)(q0 + kk) * NE + dg;
#pragma unroll
        for (int i = 0; i < 8; ++i) {
            float4 v = *(const float4*)(src + i * 16);
            const int d = dg + i * 16;
            Qs[d + 0][kk] = f2bf(v.x * scale);
            Qs[d + 1][kk] = f2bf(v.y * scale);
            Qs[d + 2][kk] = f2bf(v.z * scale);
            Qs[d + 3][kk] = f2bf(v.w * scale);
        }
    }

    float m_i[4], l_i[4], o_acc[4][8];
#pragma unroll
    for (int i = 0; i < 4; ++i) {
        m_i[i] = -INFINITY;
        l_i[i] = 0.f;
#pragma unroll
        for (int jj = 0; jj < 8; ++jj) o_acc[i][jj] = 0.f;
    }

    const int ntiles = qt + 1;
    for (int t = 0; t < ntiles; ++t) {
        const int j0 = t * 64;

        // ---- Load K tile (transposed) and V tile (straight) ----
        {
            const int kk = tid >> 2;
            const int dg = (tid & 3) * 4;
            const float* ksrc = Kg + base + (size_t)(j0 + kk) * NE + dg;
            const float* vsrc = Vg + base + (size_t)(j0 + kk) * NE + dg;
#pragma unroll
            for (int i = 0; i < 8; ++i) {
                float4 kv = *(const float4*)(ksrc + i * 16);
                const int d = dg + i * 16;
                Ks[d + 0][kk] = f2bf(kv.x);
                Ks[d + 1][kk] = f2bf(kv.y);
                Ks[d + 2][kk] = f2bf(kv.z);
                Ks[d + 3][kk] = f2bf(kv.w);
                float4 vv = *(const float4*)(vsrc + i * 16);
                ushort4 vp;
                vp.x = f2bf(vv.x); vp.y = f2bf(vv.y);
                vp.z = f2bf(vv.z); vp.w = f2bf(vv.w);
                *(ushort4*)(&Vs[kk][d]) = vp;
            }
        }
        __syncthreads();

        // ---- S = Q K^T (4x4 micro-tile, reduction over d) ----
        float s[4][4] = {};
#pragma unroll 8
        for (int d = 0; d < 128; ++d) {
            uint2 qu = *(const uint2*)(&Qs[d][4 * ty]);
            uint2 ku = *(const uint2*)(&Ks[d][4 * tx]);
            float qa[4] = {bflo(qu.x), bfhi(qu.x), bflo(qu.y), bfhi(qu.y)};
            float ka[4] = {bflo(ku.x), bfhi(ku.x), bflo(ku.y), bfhi(ku.y)};
#pragma unroll
            for (int i = 0; i < 4; ++i)
#pragma unroll
                for (int j = 0; j < 4; ++j)
                    s[i][j] += qa[i] * ka[j];
        }

        // ---- Causal mask on the diagonal tile ----
        if (t == qt) {
#pragma unroll
            for (int i = 0; i < 4; ++i)
#pragma unroll
                for (int j = 0; j < 4; ++j)
                    if (4 * tx + j > 4 * ty + i) s[i][j] = -INFINITY;
        }

        // ---- Online softmax: row max / sum across the 16 tx lanes ----
        float rmax[4];
#pragma unroll
        for (int i = 0; i < 4; ++i)
            rmax[i] = fmaxf(fmaxf(s[i][0], s[i][1]), fmaxf(s[i][2], s[i][3]));
#pragma unroll
        for (int off = 1; off < 16; off <<= 1)
#pragma unroll
            for (int i = 0; i < 4; ++i)
                rmax[i] = fmaxf(rmax[i], __shfl_xor(rmax[i], off, 64));

        float alpha[4], rsum[4];
#pragma unroll
        for (int i = 0; i < 4; ++i) {
            float mnew = fmaxf(m_i[i], rmax[i]);
            alpha[i] = __expf(m_i[i] - mnew);   // exp(-inf - finite) = 0
            m_i[i] = mnew;
            rsum[i] = 0.f;
#pragma unroll
            for (int j = 0; j < 4; ++j) {
                float p = __expf(s[i][j] - mnew);
                s[i][j] = p;
                rsum[i] += p;
            }
        }
#pragma unroll
        for (int off = 1; off < 16; off <<= 1)
#pragma unroll
            for (int i = 0; i < 4; ++i)
                rsum[i] += __shfl_xor(rsum[i], off, 64);
#pragma unroll
        for (int i = 0; i < 4; ++i) l_i[i] = l_i[i] * alpha[i] + rsum[i];

        // ---- Write P (bf16) to Ps[k][q] ----
#pragma unroll
        for (int j = 0; j < 4; ++j) {
            ushort4 pw;
            pw.x = f2bf(s[0][j]); pw.y = f2bf(s[1][j]);
            pw.z = f2bf(s[2][j]); pw.w = f2bf(s[3][j]);
            *(ushort4*)(&Ps[4 * tx + j][4 * ty]) = pw;
        }
        __syncthreads();

        // ---- O = O*alpha + P V (4x8 micro-tile, reduction over k) ----
#pragma unroll
        for (int i = 0; i < 4; ++i)
#pragma unroll
            for (int jj = 0; jj < 8; ++jj) o_acc[i][jj] *= alpha[i];

#pragma unroll 4
        for (int k = 0; k < 64; ++k) {
            uint2 pu = *(const uint2*)(&Ps[k][4 * ty]);
            float pa[4] = {bflo(pu.x), bfhi(pu.x), bflo(pu.y), bfhi(pu.y)};
            uint4 vu = *(const uint4*)(&Vs[k][8 * tx]);
            float va[8] = {bflo(vu.x), bfhi(vu.x), bflo(vu.y), bfhi(vu.y),
                           bflo(vu.z), bfhi(vu.z), bflo(vu.w), bfhi(vu.w)};
#pragma unroll
            for (int i = 0; i < 4; ++i)
#pragma unroll
                for (int jj = 0; jj < 8; ++jj)
                    o_acc[i][jj] += pa[i] * va[jj];
        }
        __syncthreads();   // protect Ks/Vs/Ps before next tile's staging
    }

    // ---- Epilogue: O /= l, write out ----
#pragma unroll
    for (int i = 0; i < 4; ++i) {
        const float inv = 1.0f / l_i[i];
        float* dst = Yg + base + (size_t)(q0 + 4 * ty + i) * NE + 8 * tx;
        float4 o0 = make_float4(o_acc[i][0] * inv, o_acc[i][1] * inv,
                                o_acc[i][2] * inv, o_acc[i][3] * inv);
        float4 o1 = make_float4(o_acc[i][4] * inv, o_acc[i][5] * inv,
                                o_acc[i][6] * inv, o_acc[i][7] * inv);
        *(float4*)(dst + 0) = o0;
        *(float4*)(dst + 4) = o1;
    }
}

// ---------------------------------------------------------------------------
extern "C" void kernel_launch(void* const* d_in, const int* in_sizes, int n_in,
                              void* d_out, int out_size, void* d_ws, size_t ws_size,
                              hipStream_t stream)
{
    const float* x  = (const float*)d_in[0];
    const float* wq = (const float*)d_in[1];
    const float* wk = (const float*)d_in[2];
    const float* wv = (const float*)d_in[3];
    const float* wo = (const float*)d_in[4];
    float* out = (float*)d_out;

    const size_t mat_elems = (size_t)MROWS * NE;
    float* Q = (float*)d_ws;
    float* K = Q + mat_elems;
    float* V = K + mat_elems;
    float* Y = Q;  // alias, safe (see flash_attn)

    dim3 gblk(16, 16);
    dim3 ggrd(NE / 64, MROWS / 64);

    gemm_f32<<<ggrd, gblk, 0, stream>>>(x, wq, Q, MROWS, NE, NE);
    gemm_f32<<<ggrd, gblk, 0, stream>>>(x, wk, K, MROWS, NE, NE);
    gemm_f32<<<ggrd, gblk, 0, stream>>>(x, wv, V, MROWS, NE, NE);

    const size_t npairs = (size_t)MROWS * NE / 2;
    dim3 rgrd((unsigned)((npairs + 255) / 256), 2);
    rope_kernel<<<rgrd, 256, 0, stream>>>(Q, K);

    dim3 agrd(SEQ / 64, BSZ * NH);  // (32, 32)
    flash_attn<<<agrd, 256, 0, stream>>>(Q, K, V, Y);

    gemm_f32<<<ggrd, gblk, 0, stream>>>(Y, wo, out, MROWS, NE, NE);
}

// Round 3
// 1432.208 us; speedup vs baseline: 7.1245x; 2.1998x over previous
//
#include <hip/hip_runtime.h>
#include <math.h>

// Problem constants (fixed by the reference)
constexpr int BSZ = 2;
constexpr int SEQ = 2048;
constexpr int NE  = 2048;   // n_embd
constexpr int NH  = 16;
constexpr int HD  = 128;    // head_dim
constexpr int MROWS = BSZ * SEQ;  // 4096

typedef __bf16 bf16x8 __attribute__((ext_vector_type(8)));
typedef float  f32x4  __attribute__((ext_vector_type(4)));

// ---------------------------------------------------------------------------
// bf16 helpers
// ---------------------------------------------------------------------------
__device__ __forceinline__ unsigned short f2bf(float f) {
    union { float f; unsigned u; } v; v.f = f;
    unsigned r = v.u + 0x7fffu + ((v.u >> 16) & 1u);   // round-to-nearest-even
    return (unsigned short)(r >> 16);
}
__device__ __forceinline__ float bf2f(unsigned short s) {
    union { unsigned u; float f; } v; v.u = ((unsigned)s) << 16; return v.f;
}
__device__ __forceinline__ float bflo(unsigned u) {
    union { unsigned u; float f; } v; v.u = u << 16; return v.f;
}
__device__ __forceinline__ float bfhi(unsigned u) {
    union { unsigned u; float f; } v; v.u = u & 0xffff0000u; return v.f;
}

// async global->LDS, 16 B per lane; lds ptr must be wave-uniform
__device__ __forceinline__ void load_lds16(const void* g, void* l) {
    __builtin_amdgcn_global_load_lds(
        (const __attribute__((address_space(1))) unsigned int*)g,
        (__attribute__((address_space(3))) unsigned int*)l, 16, 0, 0);
}

// ---------------------------------------------------------------------------
// x fp32 -> bf16 cast
// ---------------------------------------------------------------------------
__global__ __launch_bounds__(256) void cast_f32_bf16(const float* __restrict__ in,
                                                     ushort* __restrict__ out, int n)
{
    int i = (blockIdx.x * 256 + threadIdx.x) * 4;
    if (i >= n) return;
    float4 v = *(const float4*)(in + i);
    ushort4 o;
    o.x = f2bf(v.x); o.y = f2bf(v.y); o.z = f2bf(v.z); o.w = f2bf(v.w);
    *(ushort4*)(out + i) = o;
}

// ---------------------------------------------------------------------------
// Weight transpose + cast: W[K][N] fp32 -> Wt[N][K] bf16. blockIdx.z picks matrix.
// ---------------------------------------------------------------------------
__global__ __launch_bounds__(256) void transpose_cast(const float* __restrict__ w0,
                                                      const float* __restrict__ w1,
                                                      const float* __restrict__ w2,
                                                      const float* __restrict__ w3,
                                                      ushort* __restrict__ o0,
                                                      ushort* __restrict__ o1,
                                                      ushort* __restrict__ o2,
                                                      ushort* __restrict__ o3)
{
    const float* S; ushort* D;
    switch (blockIdx.z) {
        case 0: S = w0; D = o0; break;
        case 1: S = w1; D = o1; break;
        case 2: S = w2; D = o2; break;
        default: S = w3; D = o3; break;
    }
    __shared__ float t[32][33];
    const int tx = threadIdx.x, ty = threadIdx.y;
    const int x0 = blockIdx.x * 32, y0 = blockIdx.y * 32;
#pragma unroll
    for (int i = 0; i < 4; ++i)
        t[ty + i * 8][tx] = S[(size_t)(y0 + ty + i * 8) * NE + x0 + tx];
    __syncthreads();
#pragma unroll
    for (int i = 0; i < 4; ++i)
        D[(size_t)(x0 + ty + i * 8) * NE + y0 + tx] = f2bf(t[tx][ty + i * 8]);
}

// ---------------------------------------------------------------------------
// bf16 MFMA GEMM: C[M,N] = A[M,K] * Bt[N,K]^T.  (m97-style structure)
// 128x128 tile, BK=32, 256 thr = 4 waves, each wave 64x64 via 4x4 of 16x16x32.
// LDS: unpadded row-major [128][32] bf16 tiles; staging via global_load_lds
// width=16 (lane's 16B -> ldsbase + lane*16); fragment ds_read_b128 per wave
// covers a contiguous 1 KiB -> conflict-free.
// Verified layouts (learn_hip m89/m120): A-frag A[m=lane&15][k=quad*8+j];
// B-frag Bt[n=lane&15][k=quad*8+j]; C/D col=lane&15, row=quad*4+reg.
// ---------------------------------------------------------------------------
template<bool OUT_BF16>
__global__ __launch_bounds__(256) void gemm_bf16(const ushort* __restrict__ A,
                                                 const ushort* __restrict__ Bt,
                                                 void* __restrict__ Cv,
                                                 int M, int N, int K)
{
    __shared__ ushort Al[128 * 32];   // 8 KiB
    __shared__ ushort Bl[128 * 32];   // 8 KiB

    const int tid  = threadIdx.x;
    const int w    = tid >> 6;
    const int lane = tid & 63;
    const int q    = lane >> 4;       // quad 0..3
    const int r    = lane & 15;
    const int wm   = w & 1;           // wave row 0..1
    const int wn   = w >> 1;          // wave col 0..1
    const int m0 = blockIdx.y * 128;
    const int n0 = blockIdx.x * 128;

    // staging: chunk index = round*256 + tid ; row = chunk>>2, kpart = chunk&3
    const int arow0 = tid >> 2;           const int akp0 = (tid & 3) * 8;
    const int arow1 = (256 + tid) >> 2;   const int akp1 = (tid & 3) * 8;

    f32x4 acc[4][4] = {};

    for (int k0 = 0; k0 < K; k0 += 32) {
        load_lds16(A  + (size_t)(m0 + arow0) * K + k0 + akp0, &Al[(size_t)w * 512]);
        load_lds16(A  + (size_t)(m0 + arow1) * K + k0 + akp1, &Al[(size_t)(4 + w) * 512]);
        load_lds16(Bt + (size_t)(n0 + arow0) * K + k0 + akp0, &Bl[(size_t)w * 512]);
        load_lds16(Bt + (size_t)(n0 + arow1) * K + k0 + akp1, &Bl[(size_t)(4 + w) * 512]);
        __syncthreads();   // vmcnt(0) drain + barrier

        bf16x8 af[4], bfr[4];
#pragma unroll
        for (int it = 0; it < 4; ++it)
            af[it] = *(const bf16x8*)&Al[(wm * 64 + it * 16 + r) * 32 + q * 8];
#pragma unroll
        for (int jt = 0; jt < 4; ++jt)
            bfr[jt] = *(const bf16x8*)&Bl[(wn * 64 + jt * 16 + r) * 32 + q * 8];
#pragma unroll
        for (int it = 0; it < 4; ++it)
#pragma unroll
            for (int jt = 0; jt < 4; ++jt)
                acc[it][jt] = __builtin_amdgcn_mfma_f32_16x16x32_bf16(
                    af[it], bfr[jt], acc[it][jt], 0, 0, 0);
        __syncthreads();   // protect LDS before next staging
    }

#pragma unroll
    for (int it = 0; it < 4; ++it) {
        const int row = m0 + wm * 64 + it * 16 + q * 4;
#pragma unroll
        for (int jt = 0; jt < 4; ++jt) {
            const int col = n0 + wn * 64 + jt * 16 + r;
#pragma unroll
            for (int reg = 0; reg < 4; ++reg) {
                float v = acc[it][jt][reg];
                if (OUT_BF16)
                    ((ushort*)Cv)[(size_t)(row + reg) * N + col] = f2bf(v);
                else
                    ((float*)Cv)[(size_t)(row + reg) * N + col] = v;
            }
        }
    }
}

// ---------------------------------------------------------------------------
// RoPE in-place on bf16 Q and K.
// ---------------------------------------------------------------------------
__global__ __launch_bounds__(256) void rope_bf16(ushort* __restrict__ Q,
                                                 ushort* __restrict__ K)
{
    const size_t npairs = (size_t)MROWS * NE / 2;
    size_t idx = (size_t)blockIdx.x * blockDim.x + threadIdx.x;
    if (idx >= npairs) return;
    ushort* P = blockIdx.y ? K : Q;

    const int r = (int)(idx / (NE / 2));
    const int c = (int)(idx % (NE / 2));
    const int s = r % SEQ;
    const int i = c & 63;                       // freq index within head

    const float inv_freq = powf(10000.0f, -((float)i) / 64.0f);
    const float f = (float)s * inv_freq;
    float sn, cs;
    sincosf(f, &sn, &cs);

    unsigned* p = (unsigned*)(P + (size_t)r * NE) + c;
    unsigned v = *p;
    const float x1 = bf2f((unsigned short)(v & 0xffffu));
    const float x2 = bf2f((unsigned short)(v >> 16));
    const float y1 = x1 * cs - x2 * sn;
    const float y2 = x1 * sn + x2 * cs;
    *p = (unsigned)f2bf(y1) | ((unsigned)f2bf(y2) << 16);
}

// ---------------------------------------------------------------------------
// Flash attention (bf16 in/out): one block = one (b,h) x 64-row Q-tile.
// Same structure as R2, inputs/outputs bf16. Y may alias Q.
// ---------------------------------------------------------------------------
__global__ __launch_bounds__(256) void flash_attn(const ushort* __restrict__ Qg,
                                                  const ushort* __restrict__ Kg,
                                                  const ushort* __restrict__ Vg,
                                                  ushort* __restrict__ Yg)
{
    const int qt = blockIdx.x;
    const int bh = blockIdx.y;
    const int b  = bh >> 4;
    const int h  = bh & 15;
    const int tid = threadIdx.x;
    const int tx = tid & 15;
    const int ty = tid >> 4;

    __shared__ unsigned short Qs[128][68];   // [d][q]
    __shared__ unsigned short Ks[128][68];   // [d][k]
    __shared__ unsigned short Vs[64][136];   // [k][d]
    __shared__ unsigned short Ps[64][68];    // [k][q]

    const int q0 = qt * 64;
    const size_t base = (size_t)b * SEQ * NE + (size_t)h * HD;
    const float scale = 0.088388347648318447f;  // 1/sqrt(128)

    // ---- Load Q tile, transpose to Qs[d][q] ----
    {
        const int kk = tid >> 2;
        const int dg = (tid & 3) * 8;
        const ushort* src = Qg + base + (size_t)(q0 + kk) * NE + dg;
#pragma unroll
        for (int j = 0; j < 4; ++j) {
            uint4 v = *(const uint4*)(src + j * 32);
            const ushort* u = (const ushort*)&v;
            const int d = dg + j * 32;
#pragma unroll
            for (int e = 0; e < 8; ++e) Qs[d + e][kk] = u[e];
        }
    }

    float m_i[4], l_i[4], o_acc[4][8];
#pragma unroll
    for (int i = 0; i < 4; ++i) {
        m_i[i] = -INFINITY;
        l_i[i] = 0.f;
#pragma unroll
        for (int jj = 0; jj < 8; ++jj) o_acc[i][jj] = 0.f;
    }

    const int ntiles = qt + 1;
    for (int t = 0; t < ntiles; ++t) {
        const int j0 = t * 64;

        // ---- Load K (transposed) and V (straight) tiles ----
        {
            const int kk = tid >> 2;
            const int dg = (tid & 3) * 8;
            const ushort* ksrc = Kg + base + (size_t)(j0 + kk) * NE + dg;
            const ushort* vsrc = Vg + base + (size_t)(j0 + kk) * NE + dg;
#pragma unroll
            for (int j = 0; j < 4; ++j) {
                const int d = dg + j * 32;
                uint4 kv = *(const uint4*)(ksrc + j * 32);
                const ushort* u = (const ushort*)&kv;
#pragma unroll
                for (int e = 0; e < 8; ++e) Ks[d + e][kk] = u[e];
                uint4 vv = *(const uint4*)(vsrc + j * 32);
                *(uint4*)(&Vs[kk][d]) = vv;
            }
        }
        __syncthreads();

        // ---- S = Q K^T ----
        float s[4][4] = {};
#pragma unroll 8
        for (int d = 0; d < 128; ++d) {
            uint2 qu = *(const uint2*)(&Qs[d][4 * ty]);
            uint2 ku = *(const uint2*)(&Ks[d][4 * tx]);
            float qa[4] = {bflo(qu.x), bfhi(qu.x), bflo(qu.y), bfhi(qu.y)};
            float ka[4] = {bflo(ku.x), bfhi(ku.x), bflo(ku.y), bfhi(ku.y)};
#pragma unroll
            for (int i = 0; i < 4; ++i)
#pragma unroll
                for (int j = 0; j < 4; ++j)
                    s[i][j] += qa[i] * ka[j];
        }
#pragma unroll
        for (int i = 0; i < 4; ++i)
#pragma unroll
            for (int j = 0; j < 4; ++j)
                s[i][j] *= scale;

        // ---- Causal mask on the diagonal tile ----
        if (t == qt) {
#pragma unroll
            for (int i = 0; i < 4; ++i)
#pragma unroll
                for (int j = 0; j < 4; ++j)
                    if (4 * tx + j > 4 * ty + i) s[i][j] = -INFINITY;
        }

        // ---- Online softmax across the 16 tx lanes ----
        float rmax[4];
#pragma unroll
        for (int i = 0; i < 4; ++i)
            rmax[i] = fmaxf(fmaxf(s[i][0], s[i][1]), fmaxf(s[i][2], s[i][3]));
#pragma unroll
        for (int off = 1; off < 16; off <<= 1)
#pragma unroll
            for (int i = 0; i < 4; ++i)
                rmax[i] = fmaxf(rmax[i], __shfl_xor(rmax[i], off, 64));

        float alpha[4], rsum[4];
#pragma unroll
        for (int i = 0; i < 4; ++i) {
            float mnew = fmaxf(m_i[i], rmax[i]);
            alpha[i] = __expf(m_i[i] - mnew);
            m_i[i] = mnew;
            rsum[i] = 0.f;
#pragma unroll
            for (int j = 0; j < 4; ++j) {
                float p = __expf(s[i][j] - mnew);
                s[i][j] = p;
                rsum[i] += p;
            }
        }
#pragma unroll
        for (int off = 1; off < 16; off <<= 1)
#pragma unroll
            for (int i = 0; i < 4; ++i)
                rsum[i] += __shfl_xor(rsum[i], off, 64);
#pragma unroll
        for (int i = 0; i < 4; ++i) l_i[i] = l_i[i] * alpha[i] + rsum[i];

        // ---- P -> LDS (bf16, [k][q]) ----
#pragma unroll
        for (int j = 0; j < 4; ++j) {
            ushort4 pw;
            pw.x = f2bf(s[0][j]); pw.y = f2bf(s[1][j]);
            pw.z = f2bf(s[2][j]); pw.w = f2bf(s[3][j]);
            *(ushort4*)(&Ps[4 * tx + j][4 * ty]) = pw;
        }
        __syncthreads();

        // ---- O = O*alpha + P V ----
#pragma unroll
        for (int i = 0; i < 4; ++i)
#pragma unroll
            for (int jj = 0; jj < 8; ++jj) o_acc[i][jj] *= alpha[i];

#pragma unroll 4
        for (int k = 0; k < 64; ++k) {
            uint2 pu = *(const uint2*)(&Ps[k][4 * ty]);
            float pa[4] = {bflo(pu.x), bfhi(pu.x), bflo(pu.y), bfhi(pu.y)};
            uint4 vu = *(const uint4*)(&Vs[k][8 * tx]);
            float va[8] = {bflo(vu.x), bfhi(vu.x), bflo(vu.y), bfhi(vu.y),
                           bflo(vu.z), bfhi(vu.z), bflo(vu.w), bfhi(vu.w)};
#pragma unroll
            for (int i = 0; i < 4; ++i)
#pragma unroll
                for (int jj = 0; jj < 8; ++jj)
                    o_acc[i][jj] += pa[i] * va[jj];
        }
        __syncthreads();
    }

    // ---- Epilogue: O /= l, write bf16 ----
#pragma unroll
    for (int i = 0; i < 4; ++i) {
        const float inv = 1.0f / l_i[i];
        ushort* dst = Yg + base + (size_t)(q0 + 4 * ty + i) * NE + 8 * tx;
        ushort o[8];
#pragma unroll
        for (int jj = 0; jj < 8; ++jj) o[jj] = f2bf(o_acc[i][jj] * inv);
        *(uint4*)dst = *(const uint4*)o;
    }
}

// ---------------------------------------------------------------------------
extern "C" void kernel_launch(void* const* d_in, const int* in_sizes, int n_in,
                              void* d_out, int out_size, void* d_ws, size_t ws_size,
                              hipStream_t stream)
{
    const float* x  = (const float*)d_in[0];
    const float* wq = (const float*)d_in[1];
    const float* wk = (const float*)d_in[2];
    const float* wv = (const float*)d_in[3];
    const float* wo = (const float*)d_in[4];
    float* out = (float*)d_out;

    // ws layout (bf16 elements): xb | wqT | wkT | wvT | woT | Qb | Kb | Vb = 96 MiB
    ushort* ws = (ushort*)d_ws;
    const size_t MAT  = (size_t)MROWS * NE;   // 8M
    const size_t WMAT = (size_t)NE * NE;      // 4M
    ushort* xb  = ws;
    ushort* wqT = xb + MAT;
    ushort* wkT = wqT + WMAT;
    ushort* wvT = wkT + WMAT;
    ushort* woT = wvT + WMAT;
    ushort* Qb  = woT + WMAT;
    ushort* Kb  = Qb + MAT;
    ushort* Vb  = Kb + MAT;
    ushort* Yb  = Qb;   // alias, safe (flash reads its own Q slice before write)

    cast_f32_bf16<<<(unsigned)(MAT / 4 / 256), 256, 0, stream>>>(x, xb, (int)MAT);
    transpose_cast<<<dim3(64, 64, 4), dim3(32, 8), 0, stream>>>(
        wq, wk, wv, wo, wqT, wkT, wvT, woT);

    dim3 ggrd(NE / 128, MROWS / 128);  // (16, 32)
    gemm_bf16<true><<<ggrd, 256, 0, stream>>>(xb, wqT, Qb, MROWS, NE, NE);
    gemm_bf16<true><<<ggrd, 256, 0, stream>>>(xb, wkT, Kb, MROWS, NE, NE);
    gemm_bf16<true><<<ggrd, 256, 0, stream>>>(xb, wvT, Vb, MROWS, NE, NE);

    const size_t npairs = (size_t)MROWS * NE / 2;
    rope_bf16<<<dim3((unsigned)(npairs / 256), 2), 256, 0, stream>>>(Qb, Kb);

    flash_attn<<<dim3(SEQ / 64, BSZ * NH), 256, 0, stream>>>(Qb, Kb, Vb, Yb);

    gemm_bf16<false><<<ggrd, 256, 0, stream>>>(Yb, woT, out, MROWS, NE, NE);
}

// Round 4
// 560.778 us; speedup vs baseline: 18.1958x; 2.5540x over previous
//
#include <hip/hip_runtime.h>
#include <math.h>

// Problem constants (fixed by the reference)
constexpr int BSZ = 2;
constexpr int SEQ = 2048;
constexpr int NE  = 2048;   // n_embd
constexpr int NH  = 16;
constexpr int HD  = 128;    // head_dim
constexpr int MROWS = BSZ * SEQ;  // 4096

typedef __bf16 bf16x8 __attribute__((ext_vector_type(8)));
typedef float  f32x4  __attribute__((ext_vector_type(4)));

// ---------------------------------------------------------------------------
// bf16 helpers
// ---------------------------------------------------------------------------
__device__ __forceinline__ unsigned short f2bf(float f) {
    union { float f; unsigned u; } v; v.f = f;
    unsigned r = v.u + 0x7fffu + ((v.u >> 16) & 1u);   // round-to-nearest-even
    return (unsigned short)(r >> 16);
}
__device__ __forceinline__ float bf2f(unsigned short s) {
    union { unsigned u; float f; } v; v.u = ((unsigned)s) << 16; return v.f;
}

// async global->LDS, 16 B per lane; lds ptr must be wave-uniform
__device__ __forceinline__ void load_lds16(const void* g, void* l) {
    __builtin_amdgcn_global_load_lds(
        (const __attribute__((address_space(1))) unsigned int*)g,
        (__attribute__((address_space(3))) unsigned int*)l, 16, 0, 0);
}

// ---------------------------------------------------------------------------
// x fp32 -> bf16 cast
// ---------------------------------------------------------------------------
__global__ __launch_bounds__(256) void cast_f32_bf16(const float* __restrict__ in,
                                                     ushort* __restrict__ out, int n)
{
    int i = (blockIdx.x * 256 + threadIdx.x) * 4;
    if (i >= n) return;
    float4 v = *(const float4*)(in + i);
    ushort4 o;
    o.x = f2bf(v.x); o.y = f2bf(v.y); o.z = f2bf(v.z); o.w = f2bf(v.w);
    *(ushort4*)(out + i) = o;
}

// ---------------------------------------------------------------------------
// Weight transpose + cast: W[K][N] fp32 -> Wt[N][K] bf16. blockIdx.z picks matrix.
// ---------------------------------------------------------------------------
__global__ __launch_bounds__(256) void transpose_cast(const float* __restrict__ w0,
                                                      const float* __restrict__ w1,
                                                      const float* __restrict__ w2,
                                                      const float* __restrict__ w3,
                                                      ushort* __restrict__ o0,
                                                      ushort* __restrict__ o1,
                                                      ushort* __restrict__ o2,
                                                      ushort* __restrict__ o3)
{
    const float* S; ushort* D;
    switch (blockIdx.z) {
        case 0: S = w0; D = o0; break;
        case 1: S = w1; D = o1; break;
        case 2: S = w2; D = o2; break;
        default: S = w3; D = o3; break;
    }
    __shared__ float t[32][33];
    const int tx = threadIdx.x, ty = threadIdx.y;
    const int x0 = blockIdx.x * 32, y0 = blockIdx.y * 32;
#pragma unroll
    for (int i = 0; i < 4; ++i)
        t[ty + i * 8][tx] = S[(size_t)(y0 + ty + i * 8) * NE + x0 + tx];
    __syncthreads();
#pragma unroll
    for (int i = 0; i < 4; ++i)
        D[(size_t)(x0 + ty + i * 8) * NE + y0 + tx] = f2bf(t[tx][ty + i * 8]);
}

// ---------------------------------------------------------------------------
// Fused QKV GEMM: C = xb[4096,2048] * W[6144,2048]^T (W = wqT|wkT|wvT stacked).
// 128x128 tile, BK=32, m97 structure. Epilogue by n-range:
//   mat 0 -> Qb row-major bf16, mat 1 -> Kb row-major bf16,
//   mat 2 -> Vt[b][h][d][s] bf16 (per-head transposed V for flash's B-frags).
// ---------------------------------------------------------------------------
__global__ __launch_bounds__(256) void gemm_qkv(const ushort* __restrict__ A,
                                                const ushort* __restrict__ W,
                                                ushort* __restrict__ Qb,
                                                ushort* __restrict__ Kb,
                                                ushort* __restrict__ Vt)
{
    __shared__ ushort Al[128 * 32];
    __shared__ ushort Bl[128 * 32];

    const int tid  = threadIdx.x;
    const int w    = tid >> 6;
    const int lane = tid & 63;
    const int quad = lane >> 4;
    const int r    = lane & 15;
    const int wm   = w & 1;
    const int wn   = w >> 1;
    const int m0 = blockIdx.y * 128;
    const int n0 = blockIdx.x * 128;      // 0..6143 (global row in stacked W)
    const int K  = NE;

    const int arow0 = tid >> 2;           const int akp = (tid & 3) * 8;
    const int arow1 = (256 + tid) >> 2;

    f32x4 acc[4][4] = {};

    for (int k0 = 0; k0 < K; k0 += 32) {
        load_lds16(A + (size_t)(m0 + arow0) * K + k0 + akp, &Al[(size_t)w * 512]);
        load_lds16(A + (size_t)(m0 + arow1) * K + k0 + akp, &Al[(size_t)(4 + w) * 512]);
        load_lds16(W + (size_t)(n0 + arow0) * K + k0 + akp, &Bl[(size_t)w * 512]);
        load_lds16(W + (size_t)(n0 + arow1) * K + k0 + akp, &Bl[(size_t)(4 + w) * 512]);
        __syncthreads();

        bf16x8 af[4], bfr[4];
#pragma unroll
        for (int it = 0; it < 4; ++it)
            af[it] = *(const bf16x8*)&Al[(wm * 64 + it * 16 + r) * 32 + quad * 8];
#pragma unroll
        for (int jt = 0; jt < 4; ++jt)
            bfr[jt] = *(const bf16x8*)&Bl[(wn * 64 + jt * 16 + r) * 32 + quad * 8];
#pragma unroll
        for (int it = 0; it < 4; ++it)
#pragma unroll
            for (int jt = 0; jt < 4; ++jt)
                acc[it][jt] = __builtin_amdgcn_mfma_f32_16x16x32_bf16(
                    af[it], bfr[jt], acc[it][jt], 0, 0, 0);
        __syncthreads();
    }

    const int mat  = n0 >> 11;        // 0=Q,1=K,2=V
    const int ncol = n0 & 2047;
    if (mat < 2) {
        ushort* C = mat ? Kb : Qb;
#pragma unroll
        for (int it = 0; it < 4; ++it) {
            const int row = m0 + wm * 64 + it * 16 + quad * 4;
#pragma unroll
            for (int jt = 0; jt < 4; ++jt) {
                const int col = ncol + wn * 64 + jt * 16 + r;
#pragma unroll
                for (int reg = 0; reg < 4; ++reg)
                    C[(size_t)(row + reg) * NE + col] = f2bf(acc[it][jt][reg]);
            }
        }
    } else {
#pragma unroll
        for (int it = 0; it < 4; ++it) {
            const int row = m0 + wm * 64 + it * 16 + quad * 4;   // 4-aligned
            const int bb = row >> 11;
            const int s  = row & 2047;
#pragma unroll
            for (int jt = 0; jt < 4; ++jt) {
                const int col = ncol + wn * 64 + jt * 16 + r;
                const int hh = col >> 7;
                const int d  = col & 127;
                ushort4 pk;
                pk.x = f2bf(acc[it][jt][0]); pk.y = f2bf(acc[it][jt][1]);
                pk.z = f2bf(acc[it][jt][2]); pk.w = f2bf(acc[it][jt][3]);
                *(ushort4*)&Vt[((size_t)((bb * NH + hh) * HD + d)) * SEQ + s] = pk;
            }
        }
    }
}

// ---------------------------------------------------------------------------
// Output GEMM: out[4096,2048] f32 = Yb[4096,2048] bf16 * woT[2048,2048]^T
// ---------------------------------------------------------------------------
__global__ __launch_bounds__(256) void gemm_out(const ushort* __restrict__ A,
                                                const ushort* __restrict__ Bt,
                                                float* __restrict__ C)
{
    __shared__ ushort Al[128 * 32];
    __shared__ ushort Bl[128 * 32];

    const int tid  = threadIdx.x;
    const int w    = tid >> 6;
    const int lane = tid & 63;
    const int quad = lane >> 4;
    const int r    = lane & 15;
    const int wm   = w & 1;
    const int wn   = w >> 1;
    const int m0 = blockIdx.y * 128;
    const int n0 = blockIdx.x * 128;
    const int K  = NE;

    const int arow0 = tid >> 2;           const int akp = (tid & 3) * 8;
    const int arow1 = (256 + tid) >> 2;

    f32x4 acc[4][4] = {};

    for (int k0 = 0; k0 < K; k0 += 32) {
        load_lds16(A  + (size_t)(m0 + arow0) * K + k0 + akp, &Al[(size_t)w * 512]);
        load_lds16(A  + (size_t)(m0 + arow1) * K + k0 + akp, &Al[(size_t)(4 + w) * 512]);
        load_lds16(Bt + (size_t)(n0 + arow0) * K + k0 + akp, &Bl[(size_t)w * 512]);
        load_lds16(Bt + (size_t)(n0 + arow1) * K + k0 + akp, &Bl[(size_t)(4 + w) * 512]);
        __syncthreads();

        bf16x8 af[4], bfr[4];
#pragma unroll
        for (int it = 0; it < 4; ++it)
            af[it] = *(const bf16x8*)&Al[(wm * 64 + it * 16 + r) * 32 + quad * 8];
#pragma unroll
        for (int jt = 0; jt < 4; ++jt)
            bfr[jt] = *(const bf16x8*)&Bl[(wn * 64 + jt * 16 + r) * 32 + quad * 8];
#pragma unroll
        for (int it = 0; it < 4; ++it)
#pragma unroll
            for (int jt = 0; jt < 4; ++jt)
                acc[it][jt] = __builtin_amdgcn_mfma_f32_16x16x32_bf16(
                    af[it], bfr[jt], acc[it][jt], 0, 0, 0);
        __syncthreads();
    }

#pragma unroll
    for (int it = 0; it < 4; ++it) {
        const int row = m0 + wm * 64 + it * 16 + quad * 4;
#pragma unroll
        for (int jt = 0; jt < 4; ++jt) {
            const int col = n0 + wn * 64 + jt * 16 + r;
#pragma unroll
            for (int reg = 0; reg < 4; ++reg)
                C[(size_t)(row + reg) * NE + col] = acc[it][jt][reg];
        }
    }
}

// ---------------------------------------------------------------------------
// RoPE in-place on bf16 Q and K.
// ---------------------------------------------------------------------------
__global__ __launch_bounds__(256) void rope_bf16(ushort* __restrict__ Q,
                                                 ushort* __restrict__ K)
{
    const size_t npairs = (size_t)MROWS * NE / 2;
    size_t idx = (size_t)blockIdx.x * blockDim.x + threadIdx.x;
    if (idx >= npairs) return;
    ushort* P = blockIdx.y ? K : Q;

    const int r = (int)(idx / (NE / 2));
    const int c = (int)(idx % (NE / 2));
    const int s = r % SEQ;
    const int i = c & 63;

    const float inv_freq = powf(10000.0f, -((float)i) / 64.0f);
    const float f = (float)s * inv_freq;
    float sn, cs;
    sincosf(f, &sn, &cs);

    unsigned* p = (unsigned*)(P + (size_t)r * NE) + c;
    unsigned v = *p;
    const float x1 = bf2f((unsigned short)(v & 0xffffu));
    const float x2 = bf2f((unsigned short)(v >> 16));
    const float y1 = x1 * cs - x2 * sn;
    const float y2 = x1 * sn + x2 * cs;
    *p = (unsigned)f2bf(y1) | ((unsigned)f2bf(y2) << 16);
}

// ---------------------------------------------------------------------------
// MFMA flash attention. Block = 64 q-rows of one (b,h); 4 waves, wave w owns
// q strip [w*16, w*16+16). K/V tiles of 64 kv. Causal, online softmax.
//   S:  A-frag from Qs rows, B-frag from Ks rows (both [row][136] padded).
//   PV: A-frag from Ps (P round-trip through LDS), B-frag from Vts[d][72].
// Verified layouts: A[m=lane&15][k=quad*8+j]; Bt rows likewise; C/D
// col=lane&15, row=quad*4+reg. LDS 62.4 KB -> 2 blocks/CU.
// Y aliases Q safely (block writes exactly the Q slice it alone reads).
// ---------------------------------------------------------------------------
__global__ __launch_bounds__(256, 2) void flash_attn(const ushort* __restrict__ Qg,
                                                     const ushort* __restrict__ Kg,
                                                     const ushort* __restrict__ Vtg,
                                                     ushort* __restrict__ Yg)
{
    const int qt = (int)gridDim.x - 1 - (int)blockIdx.x;  // big blocks first
    const int bh = blockIdx.y;
    const int b = bh >> 4, h = bh & 15;
    const int tid  = threadIdx.x;
    const int w    = tid >> 6;
    const int lane = tid & 63;
    const int quad = lane >> 4;
    const int r    = lane & 15;

    __shared__ ushort Qs[64][136];
    __shared__ ushort Ks[64][136];
    __shared__ ushort Vts[128][72];
    __shared__ ushort Ps[64][72];

    const int q0 = qt * 64;
    const size_t qkbase = (size_t)b * SEQ * NE + (size_t)h * HD;
    const size_t vbase  = (size_t)(bh * HD) * SEQ;
    const float scale = 0.088388347648318447f;  // 1/sqrt(128)

    // ---- Stage Q tile (row-major, padded) ----
    {
        const int row0 = tid >> 4;
        const int ch   = (tid & 15) * 8;
#pragma unroll
        for (int i = 0; i < 4; ++i) {
            const int row = i * 16 + row0;
            *(uint4*)&Qs[row][ch] =
                *(const uint4*)(Qg + qkbase + (size_t)(q0 + row) * NE + ch);
        }
    }

    float m_i[4], l_i[4];
    f32x4 acc_o[8];
#pragma unroll
    for (int reg = 0; reg < 4; ++reg) { m_i[reg] = -INFINITY; l_i[reg] = 0.f; }
#pragma unroll
    for (int dt = 0; dt < 8; ++dt) acc_o[dt] = f32x4{0.f, 0.f, 0.f, 0.f};

    for (int t = 0; t <= qt; ++t) {
        const int j0 = t * 64;

        // ---- Stage K tile + Vt tile ----
        {
            const int row0 = tid >> 4;
            const int ch   = (tid & 15) * 8;
#pragma unroll
            for (int i = 0; i < 4; ++i) {
                const int row = i * 16 + row0;
                *(uint4*)&Ks[row][ch] =
                    *(const uint4*)(Kg + qkbase + (size_t)(j0 + row) * NE + ch);
            }
            const int d0  = tid >> 3;
            const int ch2 = (tid & 7) * 8;
#pragma unroll
            for (int i = 0; i < 4; ++i) {
                const int d = i * 32 + d0;
                *(uint4*)&Vts[d][ch2] =
                    *(const uint4*)(Vtg + vbase + (size_t)d * SEQ + j0 + ch2);
            }
        }
        __syncthreads();

        // ---- S = Q K^T (wave strip: 16q x 64kv) ----
        bf16x8 aq[4];
#pragma unroll
        for (int kc = 0; kc < 4; ++kc)
            aq[kc] = *(const bf16x8*)&Qs[w * 16 + r][kc * 32 + quad * 8];

        f32x4 sa[4];
#pragma unroll
        for (int jt = 0; jt < 4; ++jt) {
            f32x4 acc = {0.f, 0.f, 0.f, 0.f};
#pragma unroll
            for (int kc = 0; kc < 4; ++kc) {
                bf16x8 bk = *(const bf16x8*)&Ks[jt * 16 + r][kc * 32 + quad * 8];
                acc = __builtin_amdgcn_mfma_f32_16x16x32_bf16(aq[kc], bk, acc, 0, 0, 0);
            }
            sa[jt] = acc;
        }

        // ---- scale + causal mask (diag tile only) ----
        if (t == qt) {
#pragma unroll
            for (int jt = 0; jt < 4; ++jt)
#pragma unroll
                for (int reg = 0; reg < 4; ++reg)
                    sa[jt][reg] = (jt * 16 + r > w * 16 + quad * 4 + reg)
                                  ? -INFINITY : sa[jt][reg] * scale;
        } else {
#pragma unroll
            for (int jt = 0; jt < 4; ++jt)
#pragma unroll
                for (int reg = 0; reg < 4; ++reg)
                    sa[jt][reg] *= scale;
        }

        // ---- online softmax (row = quad*4+reg; reduce over 16 col lanes) ----
        float rmax[4], alpha[4], rsum[4];
#pragma unroll
        for (int reg = 0; reg < 4; ++reg)
            rmax[reg] = fmaxf(fmaxf(sa[0][reg], sa[1][reg]),
                              fmaxf(sa[2][reg], sa[3][reg]));
#pragma unroll
        for (int off = 1; off < 16; off <<= 1)
#pragma unroll
            for (int reg = 0; reg < 4; ++reg)
                rmax[reg] = fmaxf(rmax[reg], __shfl_xor(rmax[reg], off, 64));

#pragma unroll
        for (int reg = 0; reg < 4; ++reg) {
            const float mnew = fmaxf(m_i[reg], rmax[reg]);
            alpha[reg] = __expf(m_i[reg] - mnew);
            m_i[reg] = mnew;
            rsum[reg] = 0.f;
        }
#pragma unroll
        for (int jt = 0; jt < 4; ++jt)
#pragma unroll
            for (int reg = 0; reg < 4; ++reg) {
                const float p = __expf(sa[jt][reg] - m_i[reg]);
                sa[jt][reg] = p;
                rsum[reg] += p;
            }
#pragma unroll
        for (int off = 1; off < 16; off <<= 1)
#pragma unroll
            for (int reg = 0; reg < 4; ++reg)
                rsum[reg] += __shfl_xor(rsum[reg], off, 64);
#pragma unroll
        for (int reg = 0; reg < 4; ++reg)
            l_i[reg] = l_i[reg] * alpha[reg] + rsum[reg];

        // ---- P -> LDS (C-layout -> A-layout round-trip) ----
#pragma unroll
        for (int jt = 0; jt < 4; ++jt)
#pragma unroll
            for (int reg = 0; reg < 4; ++reg)
                Ps[w * 16 + quad * 4 + reg][jt * 16 + r] = f2bf(sa[jt][reg]);
        __syncthreads();

        // ---- O = O*alpha + P V ----
#pragma unroll
        for (int dt = 0; dt < 8; ++dt)
#pragma unroll
            for (int reg = 0; reg < 4; ++reg)
                acc_o[dt][reg] *= alpha[reg];

        bf16x8 ap[2];
#pragma unroll
        for (int kc = 0; kc < 2; ++kc)
            ap[kc] = *(const bf16x8*)&Ps[w * 16 + r][kc * 32 + quad * 8];
#pragma unroll
        for (int dt = 0; dt < 8; ++dt)
#pragma unroll
            for (int kc = 0; kc < 2; ++kc) {
                bf16x8 bv = *(const bf16x8*)&Vts[dt * 16 + r][kc * 32 + quad * 8];
                acc_o[dt] = __builtin_amdgcn_mfma_f32_16x16x32_bf16(ap[kc], bv, acc_o[dt], 0, 0, 0);
            }
        __syncthreads();   // protect Ks/Vts/Ps before next staging
    }

    // ---- Epilogue: O /= l, write bf16 ----
#pragma unroll
    for (int reg = 0; reg < 4; ++reg) {
        const float inv = 1.0f / l_i[reg];
        const size_t rowbase = qkbase + (size_t)(q0 + w * 16 + quad * 4 + reg) * NE;
#pragma unroll
        for (int dt = 0; dt < 8; ++dt)
            Yg[rowbase + dt * 16 + r] = f2bf(acc_o[dt][reg] * inv);
    }
}

// ---------------------------------------------------------------------------
extern "C" void kernel_launch(void* const* d_in, const int* in_sizes, int n_in,
                              void* d_out, int out_size, void* d_ws, size_t ws_size,
                              hipStream_t stream)
{
    const float* x  = (const float*)d_in[0];
    const float* wq = (const float*)d_in[1];
    const float* wk = (const float*)d_in[2];
    const float* wv = (const float*)d_in[3];
    const float* wo = (const float*)d_in[4];
    float* out = (float*)d_out;

    // ws (bf16 elems): xb | wqT wkT wvT woT | Qb | Kb | Vt   = 96 MiB
    ushort* ws = (ushort*)d_ws;
    const size_t MAT  = (size_t)MROWS * NE;   // 8M
    const size_t WMAT = (size_t)NE * NE;      // 4M
    ushort* xb  = ws;
    ushort* wqT = xb + MAT;
    ushort* wkT = wqT + WMAT;
    ushort* wvT = wkT + WMAT;
    ushort* woT = wvT + WMAT;
    ushort* Qb  = woT + WMAT;
    ushort* Kb  = Qb + MAT;
    ushort* Vt  = Kb + MAT;
    ushort* Yb  = Qb;   // alias, safe (see flash_attn)

    cast_f32_bf16<<<(unsigned)(MAT / 4 / 256), 256, 0, stream>>>(x, xb, (int)MAT);
    transpose_cast<<<dim3(64, 64, 4), dim3(32, 8), 0, stream>>>(
        wq, wk, wv, wo, wqT, wkT, wvT, woT);

    // Fused QKV: W = wqT|wkT|wvT stacked (contiguous) = [6144][2048]
    gemm_qkv<<<dim3(48, 32), 256, 0, stream>>>(xb, wqT, Qb, Kb, Vt);

    const size_t npairs = (size_t)MROWS * NE / 2;
    rope_bf16<<<dim3((unsigned)(npairs / 256), 2), 256, 0, stream>>>(Qb, Kb);

    flash_attn<<<dim3(SEQ / 64, BSZ * NH), 256, 0, stream>>>(Qb, Kb, Vt, Yb);

    gemm_out<<<dim3(16, 32), 256, 0, stream>>>(Yb, woT, out);
}